// Round 1
// baseline (403.186 us; speedup 1.0000x reference)
//
#include <hip/hip_runtime.h>
#include <math.h>

#define BB 64
#define T_SUB 512
#define WW 256
#define DD 768
#define HH 20
#define CAP_DIM 10
#define IN_DIM 778
#define KPAD 800
#define G4 80     // 4*H
#define NOUT 160  // both directions fused

// ws layout (floats):
//   x    : [BB*WW][KPAD]          = 16384*800  = 13,107,200
//   wpad : [NOUT][KPAD]           = 160*800    =    128,000
//   gpre : [BB*WW][NOUT]          = 16384*160  =  2,621,440
#define X_OFF   ((size_t)0)
#define WP_OFF  ((size_t)13107200)
#define GP_OFF  ((size_t)(13107200 + 128000))

// ---------------- K0: pad + fuse the two input-projection weight matrices ----
__global__ __launch_bounds__(256) void k_pad_w(
    const float* __restrict__ wf, const float* __restrict__ wb,
    float* __restrict__ wp)
{
    int j = blockIdx.x;  // 0..159
    const float* src = (j < G4) ? (wf + (size_t)j * IN_DIM)
                                : (wb + (size_t)(j - G4) * IN_DIM);
    for (int k = threadIdx.x; k < KPAD; k += 256)
        wp[(size_t)j * KPAD + k] = (k < IN_DIM) ? src[k] : 0.f;
}

// ---------------- K1: layer-mean + segment(word)-mean + cap concat ----------
__global__ __launch_bounds__(256) void k_build_x(
    const float* __restrict__ hiddens, const int* __restrict__ b2t,
    const int* __restrict__ cap_inds, const float* __restrict__ cap_table,
    float* __restrict__ x)
{
    int bw = blockIdx.x;
    int b = bw / WW, w = bw % WW;
    __shared__ int sh_lo, sh_cnt;
    if (threadIdx.x == 0) {
        const int* row = b2t + (size_t)b * T_SUB;
        // rows of bert2toks are non-decreasing (repeat(arange)) -> binary search
        int lo = 0, hi = T_SUB;
        while (lo < hi) { int m = (lo + hi) >> 1; if (row[m] < w) lo = m + 1; else hi = m; }
        int lo2 = lo, hi2 = T_SUB;
        while (lo2 < hi2) { int m = (lo2 + hi2) >> 1; if (row[m] < w + 1) lo2 = m + 1; else hi2 = m; }
        sh_lo = lo; sh_cnt = lo2 - lo;
    }
    __syncthreads();
    int lo = sh_lo, cnt = sh_cnt;
    float inv = 1.0f / (3.0f * (float)(cnt > 0 ? cnt : 1));
    float* xrow = x + (size_t)bw * KPAD;
    const size_t LSTR = (size_t)BB * (T_SUB + 1) * DD;  // layer stride
    for (int d = threadIdx.x; d < DD; d += 256) {
        float s = 0.f;
        for (int t = lo; t < lo + cnt; ++t) {
            size_t base = ((size_t)b * (T_SUB + 1) + (t + 1)) * DD + d;
            s += hiddens[base] + hiddens[LSTR + base] + hiddens[2 * LSTR + base];
        }
        xrow[d] = s * inv;
    }
    for (int d = DD + threadIdx.x; d < KPAD; d += 256) {
        if (d < DD + CAP_DIM) {
            int ci = cap_inds[(size_t)b * WW + w];
            xrow[d] = cap_table[ci * CAP_DIM + (d - DD)];
        } else {
            xrow[d] = 0.f;
        }
    }
}

// ---------------- K2: input projection GEMM  gpre = x @ wpad^T --------------
// M=16384, K=800(padded, zeros beyond 778), N=160. Tile 64x160, BK=32.
#define BM 64
#define BK 32
__global__ __launch_bounds__(256) void k_gemm(
    const float* __restrict__ x, const float* __restrict__ wp,
    float* __restrict__ gpre)
{
    __shared__ float xs[BM][36];     // stride 36 floats: 16B-aligned rows
    __shared__ float wsh[NOUT][38];  // stride 38: odd*2 -> <=2-way bank conflict
    int t = threadIdx.x;
    int row0 = blockIdx.x * BM;
    int tc = t & 31, tr = t >> 5;    // tc 0..31, tr 0..7
    int j0 = tc * 5, r0 = tr * 8;
    float acc[8][5];
#pragma unroll
    for (int i = 0; i < 8; i++)
#pragma unroll
        for (int c = 0; c < 5; c++) acc[i][c] = 0.f;

    for (int k0 = 0; k0 < KPAD; k0 += BK) {
        __syncthreads();
        // stage x tile: 64x32 = 512 float4
        for (int s = t; s < 512; s += 256) {
            int r = s >> 3, kc = s & 7;
            float4 v = *(const float4*)(x + (size_t)(row0 + r) * KPAD + k0 + kc * 4);
            *(float4*)(&xs[r][kc * 4]) = v;
        }
        // stage w tile: 160x32 = 1280 float4 (scalar LDS writes, stride 38)
        for (int s = t; s < 1280; s += 256) {
            int j = s >> 3, kc = s & 7;
            float4 v = *(const float4*)(wp + (size_t)j * KPAD + k0 + kc * 4);
            wsh[j][kc * 4 + 0] = v.x; wsh[j][kc * 4 + 1] = v.y;
            wsh[j][kc * 4 + 2] = v.z; wsh[j][kc * 4 + 3] = v.w;
        }
        __syncthreads();
#pragma unroll
        for (int kk = 0; kk < BK; ++kk) {
            float xv[8], wv[5];
#pragma unroll
            for (int i = 0; i < 8; i++) xv[i] = xs[r0 + i][kk];
#pragma unroll
            for (int c = 0; c < 5; c++) wv[c] = wsh[j0 + c][kk];
#pragma unroll
            for (int i = 0; i < 8; i++)
#pragma unroll
                for (int c = 0; c < 5; c++) acc[i][c] += xv[i] * wv[c];
        }
    }
#pragma unroll
    for (int i = 0; i < 8; i++) {
        int row = row0 + r0 + i;
#pragma unroll
        for (int c = 0; c < 5; c++)
            gpre[(size_t)row * NOUT + j0 + c] = acc[i][c];
    }
}

// ---------------- K3: recurrent LSTM (both dirs, batch-parallel blocks) -----
// grid = 16: blockIdx = dir*8 + batch_group(8 batches each). block = 640 thr.
__device__ __forceinline__ float fsig(float v) { return 1.f / (1.f + __expf(-v)); }
__device__ __forceinline__ float ftanh(float v) { return 2.f / (1.f + __expf(-2.f * v)) - 1.f; }

__global__ __launch_bounds__(640) void k_lstm(
    const float* __restrict__ gpre,
    const float* __restrict__ whh_f, const float* __restrict__ whh_b,
    const float* __restrict__ bias_f, const float* __restrict__ bias_b,
    float* __restrict__ out)
{
    __shared__ float whh_s[G4][21];      // stride 21 (odd) -> conflict-free
    __shared__ float bias_s[G4];
    __shared__ float h_s[8][HH], c_s[8][HH], g_s[8][G4];
    int dir = blockIdx.x >> 3;
    int bg  = blockIdx.x & 7;
    int t = threadIdx.x;
    int bl = t / G4, j = t % G4;         // bl 0..7 local batch, j gate idx
    const float* whh  = dir ? whh_b  : whh_f;
    const float* bias = dir ? bias_b : bias_f;
    for (int idx = t; idx < G4 * HH; idx += 640) whh_s[idx / HH][idx % HH] = whh[idx];
    if (t < G4) bias_s[t] = bias[t];
    if (t < 8 * HH) { h_s[t / HH][t % HH] = 0.f; c_s[t / HH][t % HH] = 0.f; }
    __syncthreads();
    int b = bg * 8 + bl;
    for (int s = 0; s < WW; ++s) {
        int w = dir ? (WW - 1 - s) : s;
        float g = gpre[((size_t)b * WW + w) * NOUT + dir * G4 + j] + bias_s[j];
#pragma unroll
        for (int k = 0; k < HH; k++) g += h_s[bl][k] * whh_s[j][k];
        g_s[bl][j] = g;
        __syncthreads();
        if (t < 8 * HH) {
            int b2 = t / HH, hj = t % HH;
            float gi = g_s[b2][hj], gf = g_s[b2][HH + hj];
            float gg = g_s[b2][2 * HH + hj], go = g_s[b2][3 * HH + hj];
            float c = fsig(gf) * c_s[b2][hj] + fsig(gi) * ftanh(gg);
            float h = fsig(go) * ftanh(c);
            c_s[b2][hj] = c; h_s[b2][hj] = h;
            int bb = bg * 8 + b2;
            out[((size_t)bb * WW + w) * (2 * HH) + dir * HH + hj] = h;
        }
        __syncthreads();
    }
}

extern "C" void kernel_launch(void* const* d_in, const int* in_sizes, int n_in,
                              void* d_out, int out_size, void* d_ws, size_t ws_size,
                              hipStream_t stream) {
    const float* hiddens   = (const float*)d_in[0];
    const int*   bert2toks = (const int*)d_in[1];
    const int*   cap_inds  = (const int*)d_in[2];
    const float* cap_table = (const float*)d_in[3];
    const float* w_ih_f    = (const float*)d_in[4];
    const float* w_hh_f    = (const float*)d_in[5];
    const float* b_f       = (const float*)d_in[6];
    const float* w_ih_b    = (const float*)d_in[7];
    const float* w_hh_b    = (const float*)d_in[8];
    const float* b_b       = (const float*)d_in[9];
    float* out = (float*)d_out;

    float* ws   = (float*)d_ws;
    float* x    = ws + X_OFF;
    float* wpad = ws + WP_OFF;
    float* gpre = ws + GP_OFF;

    k_pad_w<<<NOUT, 256, 0, stream>>>(w_ih_f, w_ih_b, wpad);
    k_build_x<<<BB * WW, 256, 0, stream>>>(hiddens, bert2toks, cap_inds, cap_table, x);
    k_gemm<<<(BB * WW) / BM, 256, 0, stream>>>(x, wpad, gpre);
    k_lstm<<<16, 640, 0, stream>>>(gpre, w_hh_f, w_hh_b, b_f, b_b, out);
}

// Round 2
// 328.940 us; speedup vs baseline: 1.2257x; 1.2257x over previous
//
#include <hip/hip_runtime.h>
#include <math.h>

#define BB 64
#define T_SUB 512
#define WW 256
#define DD 768
#define HH 20
#define CAP_DIM 10
#define IN_DIM 778
#define KPAD 800
#define G4 80     // 4*H
#define NOUT 160  // both directions fused

// ws layout (floats):
//   x    : [BB*WW][KPAD]          = 16384*800  = 13,107,200
//   wpad : [NOUT][KPAD]           = 160*800    =    128,000
//   gpre : [BB*WW][NOUT]          = 16384*160  =  2,621,440
#define X_OFF   ((size_t)0)
#define WP_OFF  ((size_t)13107200)
#define GP_OFF  ((size_t)(13107200 + 128000))

// ---------------- K0: pad + fuse the two input-projection weight matrices ----
__global__ __launch_bounds__(256) void k_pad_w(
    const float* __restrict__ wf, const float* __restrict__ wb,
    float* __restrict__ wp)
{
    int j = blockIdx.x;  // 0..159
    const float* src = (j < G4) ? (wf + (size_t)j * IN_DIM)
                                : (wb + (size_t)(j - G4) * IN_DIM);
    for (int k = threadIdx.x; k < KPAD; k += 256)
        wp[(size_t)j * KPAD + k] = (k < IN_DIM) ? src[k] : 0.f;
}

// ---------------- K1: layer-mean + segment(word)-mean + cap concat ----------
__global__ __launch_bounds__(256) void k_build_x(
    const float* __restrict__ hiddens, const int* __restrict__ b2t,
    const int* __restrict__ cap_inds, const float* __restrict__ cap_table,
    float* __restrict__ x)
{
    int bw = blockIdx.x;
    int b = bw / WW, w = bw % WW;
    __shared__ int sh_lo, sh_cnt;
    if (threadIdx.x == 0) {
        const int* row = b2t + (size_t)b * T_SUB;
        // rows of bert2toks are non-decreasing (repeat(arange)) -> binary search
        int lo = 0, hi = T_SUB;
        while (lo < hi) { int m = (lo + hi) >> 1; if (row[m] < w) lo = m + 1; else hi = m; }
        int lo2 = lo, hi2 = T_SUB;
        while (lo2 < hi2) { int m = (lo2 + hi2) >> 1; if (row[m] < w + 1) lo2 = m + 1; else hi2 = m; }
        sh_lo = lo; sh_cnt = lo2 - lo;
    }
    __syncthreads();
    int lo = sh_lo, cnt = sh_cnt;
    float inv = 1.0f / (3.0f * (float)(cnt > 0 ? cnt : 1));
    float* xrow = x + (size_t)bw * KPAD;
    const size_t LSTR = (size_t)BB * (T_SUB + 1) * DD;  // layer stride
    for (int d = threadIdx.x; d < DD; d += 256) {
        float s = 0.f;
        for (int t = lo; t < lo + cnt; ++t) {
            size_t base = ((size_t)b * (T_SUB + 1) + (t + 1)) * DD + d;
            s += hiddens[base] + hiddens[LSTR + base] + hiddens[2 * LSTR + base];
        }
        xrow[d] = s * inv;
    }
    for (int d = DD + threadIdx.x; d < KPAD; d += 256) {
        if (d < DD + CAP_DIM) {
            int ci = cap_inds[(size_t)b * WW + w];
            xrow[d] = cap_table[ci * CAP_DIM + (d - DD)];
        } else {
            xrow[d] = 0.f;
        }
    }
}

// ---------------- K2: input projection GEMM  gpre = x @ wpad^T --------------
// M=16384, K=800(padded, zeros beyond 778), N=160. Tile 32x160, BK=32.
// BM=32 -> 512 blocks = 2 blocks/CU so staging overlaps FMA issue.
#define BM 32
#define BK 32
__global__ __launch_bounds__(256) void k_gemm(
    const float* __restrict__ x, const float* __restrict__ wp,
    float* __restrict__ gpre)
{
    __shared__ float xs[BM][36];     // stride 36 floats: 16B-aligned rows
    __shared__ float wsh[NOUT][38];  // stride 38: 2-way bank conflict max (free)
    int t = threadIdx.x;
    int row0 = blockIdx.x * BM;
    int tc = t & 31, tr = t >> 5;    // tc 0..31, tr 0..7
    int j0 = tc * 5, r0 = tr * 4;
    float acc[4][5];
#pragma unroll
    for (int i = 0; i < 4; i++)
#pragma unroll
        for (int c = 0; c < 5; c++) acc[i][c] = 0.f;

    for (int k0 = 0; k0 < KPAD; k0 += BK) {
        __syncthreads();
        // stage x tile: 32x32 = 256 float4 (one per thread)
        {
            int r = t >> 3, kc = t & 7;
            if (t < 256) {
                float4 v = *(const float4*)(x + (size_t)(row0 + r) * KPAD + k0 + kc * 4);
                *(float4*)(&xs[r][kc * 4]) = v;
            }
        }
        // stage w tile: 160x32 = 1280 float4 (scalar LDS writes, stride 38)
        for (int s = t; s < 1280; s += 256) {
            int j = s >> 3, kc = s & 7;
            float4 v = *(const float4*)(wp + (size_t)j * KPAD + k0 + kc * 4);
            wsh[j][kc * 4 + 0] = v.x; wsh[j][kc * 4 + 1] = v.y;
            wsh[j][kc * 4 + 2] = v.z; wsh[j][kc * 4 + 3] = v.w;
        }
        __syncthreads();
#pragma unroll
        for (int kk = 0; kk < BK; ++kk) {
            float xv[4], wv[5];
#pragma unroll
            for (int i = 0; i < 4; i++) xv[i] = xs[r0 + i][kk];
#pragma unroll
            for (int c = 0; c < 5; c++) wv[c] = wsh[j0 + c][kk];
#pragma unroll
            for (int i = 0; i < 4; i++)
#pragma unroll
                for (int c = 0; c < 5; c++) acc[i][c] += xv[i] * wv[c];
        }
    }
#pragma unroll
    for (int i = 0; i < 4; i++) {
        int row = row0 + r0 + i;
#pragma unroll
        for (int c = 0; c < 5; c++)
            gpre[(size_t)row * NOUT + j0 + c] = acc[i][c];
    }
}

// ---------------- K3: recurrent LSTM, single-wave blocks, no barriers -------
// grid = 128: blockIdx = dir*64 + b. block = 64 threads (1 wave).
// Lane j<40 owns gates j and j+40 (w_hh rows in registers).
// Gate layout: i=0..19, f=20..39, g=40..59, o=60..79.
//   lane j<20:      a0 = i_j,     a1 = g_j
//   lane 20<=j<40:  a0 = f_{j-20}, a1 = o_{j-20}
// h broadcast via __shfl (wave-synchronous); gpre prefetched 1 step ahead.
__device__ __forceinline__ float fsig(float v) { return 1.f / (1.f + __expf(-v)); }
__device__ __forceinline__ float ftanh(float v) { return 2.f / (1.f + __expf(-2.f * v)) - 1.f; }

__global__ __launch_bounds__(64) void k_lstm(
    const float* __restrict__ gpre,
    const float* __restrict__ whh_f, const float* __restrict__ whh_b,
    const float* __restrict__ bias_f, const float* __restrict__ bias_b,
    float* __restrict__ out)
{
    int dir  = blockIdx.x >> 6;   // grid = 128
    int b    = blockIdx.x & 63;
    int lane = threadIdx.x;
    const float* whh  = dir ? whh_b  : whh_f;
    const float* bias = dir ? bias_b : bias_f;

    int g0 = (lane < 40) ? lane : 39;   // clamp idle lanes to valid memory
    int g1 = g0 + 40;
    float w0[HH], w1[HH];
#pragma unroll
    for (int k = 0; k < HH; k++) {
        w0[k] = whh[g0 * HH + k];
        w1[k] = whh[g1 * HH + k];
    }
    float b0 = bias[g0], b1 = bias[g1];

    const float* gp = gpre + (size_t)b * WW * NOUT + dir * G4;
    float h = 0.f, c = 0.f;             // live in lanes < 20
    int w = dir ? (WW - 1) : 0;
    int stepd = dir ? -1 : 1;
    float pre0 = gp[(size_t)w * NOUT + g0];
    float pre1 = gp[(size_t)w * NOUT + g1];

    for (int s = 0; s < WW; ++s) {
        int wn = w + stepd;
        float n0 = 0.f, n1 = 0.f;
        if (s + 1 < WW) {               // prefetch next step (independent of h)
            n0 = gp[(size_t)wn * NOUT + g0];
            n1 = gp[(size_t)wn * NOUT + g1];
        }
        float a0 = pre0 + b0, a1 = pre1 + b1;
#pragma unroll
        for (int k = 0; k < HH; k++) {
            float hv = __shfl(h, k, 64);
            a0 = fmaf(hv, w0[k], a0);
            a1 = fmaf(hv, w1[k], a1);
        }
        int src = (lane % 20) + 20;
        float fv = __shfl(a0, src, 64);
        float ov = __shfl(a1, src, 64);
        if (lane < HH) {
            c = fsig(fv) * c + fsig(a0) * ftanh(a1);
            h = fsig(ov) * ftanh(c);
            out[((size_t)b * WW + w) * (2 * HH) + dir * HH + lane] = h;
        }
        pre0 = n0; pre1 = n1;
        w = wn;
    }
}

extern "C" void kernel_launch(void* const* d_in, const int* in_sizes, int n_in,
                              void* d_out, int out_size, void* d_ws, size_t ws_size,
                              hipStream_t stream) {
    const float* hiddens   = (const float*)d_in[0];
    const int*   bert2toks = (const int*)d_in[1];
    const int*   cap_inds  = (const int*)d_in[2];
    const float* cap_table = (const float*)d_in[3];
    const float* w_ih_f    = (const float*)d_in[4];
    const float* w_hh_f    = (const float*)d_in[5];
    const float* b_f       = (const float*)d_in[6];
    const float* w_ih_b    = (const float*)d_in[7];
    const float* w_hh_b    = (const float*)d_in[8];
    const float* b_b       = (const float*)d_in[9];
    float* out = (float*)d_out;

    float* ws   = (float*)d_ws;
    float* x    = ws + X_OFF;
    float* wpad = ws + WP_OFF;
    float* gpre = ws + GP_OFF;

    k_pad_w<<<NOUT, 256, 0, stream>>>(w_ih_f, w_ih_b, wpad);
    k_build_x<<<BB * WW, 256, 0, stream>>>(hiddens, bert2toks, cap_inds, cap_table, x);
    k_gemm<<<(BB * WW) / BM, 256, 0, stream>>>(x, wpad, gpre);
    k_lstm<<<128, 64, 0, stream>>>(gpre, w_hh_f, w_hh_b, b_f, b_b, out);
}

// Round 3
// 266.129 us; speedup vs baseline: 1.5150x; 1.2360x over previous
//
#include <hip/hip_runtime.h>
#include <math.h>

#define BB 64
#define T_SUB 512
#define WW 256
#define DD 768
#define HH 20
#define CAP_DIM 10
#define IN_DIM 778
#define KPAD 800
#define G4 80     // 4*H
#define NOUT 160  // both directions fused

typedef _Float16 f16x8 __attribute__((ext_vector_type(8)));
typedef float f32x4 __attribute__((ext_vector_type(4)));

// ws layout (bytes):
//   x    : [16384][800] f16  = 26,214,400
//   wpad : [160][800]  f16   =    256,000
//   gpre : [16384][160] f32  = 10,485,760
#define X_BYTES   ((size_t)26214400)
#define WP_BYTES  ((size_t)256000)

// ---------------- K0: pad + fuse input-projection weights -> fp16 -----------
__global__ __launch_bounds__(256) void k_pad_w(
    const float* __restrict__ wf, const float* __restrict__ wb,
    _Float16* __restrict__ wp)
{
    int j = blockIdx.x;  // 0..159
    const float* src = (j < G4) ? (wf + (size_t)j * IN_DIM)
                                : (wb + (size_t)(j - G4) * IN_DIM);
    for (int k = threadIdx.x; k < KPAD; k += 256)
        wp[(size_t)j * KPAD + k] = (k < IN_DIM) ? (_Float16)src[k] : (_Float16)0.f;
}

// ---------------- K1: layer-mean + word-mean + cap concat -> fp16 x ---------
__global__ __launch_bounds__(256) void k_build_x(
    const float* __restrict__ hiddens, const int* __restrict__ b2t,
    const int* __restrict__ cap_inds, const float* __restrict__ cap_table,
    _Float16* __restrict__ x)
{
    int bw = blockIdx.x;
    int b = bw / WW, w = bw % WW;
    __shared__ int sh_lo, sh_cnt;
    if (threadIdx.x == 0) {
        const int* row = b2t + (size_t)b * T_SUB;
        int lo = 0, hi = T_SUB;
        while (lo < hi) { int m = (lo + hi) >> 1; if (row[m] < w) lo = m + 1; else hi = m; }
        int lo2 = lo, hi2 = T_SUB;
        while (lo2 < hi2) { int m = (lo2 + hi2) >> 1; if (row[m] < w + 1) lo2 = m + 1; else hi2 = m; }
        sh_lo = lo; sh_cnt = lo2 - lo;
    }
    __syncthreads();
    int lo = sh_lo, cnt = sh_cnt;
    float inv = 1.0f / (3.0f * (float)(cnt > 0 ? cnt : 1));
    _Float16* xrow = x + (size_t)bw * KPAD;
    const size_t LSTR = (size_t)BB * (T_SUB + 1) * DD;  // layer stride
    for (int d = threadIdx.x; d < DD; d += 256) {
        float s = 0.f;
        for (int t = lo; t < lo + cnt; ++t) {
            size_t base = ((size_t)b * (T_SUB + 1) + (t + 1)) * DD + d;
            s += hiddens[base] + hiddens[LSTR + base] + hiddens[2 * LSTR + base];
        }
        xrow[d] = (_Float16)(s * inv);
    }
    for (int d = DD + threadIdx.x; d < KPAD; d += 256) {
        if (d < DD + CAP_DIM) {
            int ci = cap_inds[(size_t)b * WW + w];
            xrow[d] = (_Float16)cap_table[ci * CAP_DIM + (d - DD)];
        } else {
            xrow[d] = (_Float16)0.f;
        }
    }
}

// ---------------- K2: MFMA fp16 GEMM  gpre = x @ wpad^T ---------------------
// M=16384, K=800, N=160. Block tile 64x160, 4 waves (16 m-rows each), BK=32.
// LDS rows padded to 40 f16 (80 B): b128-aligned, <=2-way bank alias (free).
#define BMT 64
#define BKT 32
__global__ __launch_bounds__(256) void k_gemm(
    const _Float16* __restrict__ x, const _Float16* __restrict__ wp,
    float* __restrict__ gpre)
{
    __shared__ _Float16 As[BMT][40];
    __shared__ _Float16 Ws[NOUT][40];
    int t = threadIdx.x;
    int wv = t >> 6;
    int lane = t & 63;
    int row0 = blockIdx.x * BMT;
    f32x4 acc[10];
#pragma unroll
    for (int i = 0; i < 10; i++)
#pragma unroll
        for (int r = 0; r < 4; r++) acc[i][r] = 0.f;

    for (int k0 = 0; k0 < KPAD; k0 += BKT) {
        __syncthreads();
        {   // stage A tile: 64 rows x 32 f16 (4 chunks of 16B) — 256 loads
            int r = t >> 2, ch = t & 3;
            float4 v = *(const float4*)(x + (size_t)(row0 + r) * KPAD + k0 + ch * 8);
            *(float4*)(&As[r][ch * 8]) = v;
        }
        // stage W tile: 160 rows x 4 chunks = 640 loads
        for (int s = t; s < 640; s += 256) {
            int r = s >> 2, ch = s & 3;
            float4 v = *(const float4*)(wp + (size_t)r * KPAD + k0 + ch * 8);
            *(float4*)(&Ws[r][ch * 8]) = v;
        }
        __syncthreads();
        int arow = wv * 16 + (lane & 15);
        int koff = (lane >> 4) * 8;
        f16x8 afrag = *(const f16x8*)(&As[arow][koff]);
#pragma unroll
        for (int nf = 0; nf < 10; nf++) {
            f16x8 bfrag = *(const f16x8*)(&Ws[nf * 16 + (lane & 15)][koff]);
            acc[nf] = __builtin_amdgcn_mfma_f32_16x16x32_f16(afrag, bfrag, acc[nf], 0, 0, 0);
        }
    }
    // C/D layout: col = lane&15, row = (lane>>4)*4 + reg  [m89-verified]
    int orow = row0 + wv * 16 + (lane >> 4) * 4;
    int ocol = lane & 15;
#pragma unroll
    for (int nf = 0; nf < 10; nf++)
#pragma unroll
        for (int r = 0; r < 4; r++)
            gpre[(size_t)(orow + r) * NOUT + nf * 16 + ocol] = acc[nf][r];
}

// ---------------- K3: recurrent LSTM, single-wave blocks, no barriers -------
__device__ __forceinline__ float fsig(float v) { return 1.f / (1.f + __expf(-v)); }
__device__ __forceinline__ float ftanh(float v) { return 2.f / (1.f + __expf(-2.f * v)) - 1.f; }

__global__ __launch_bounds__(64) void k_lstm(
    const float* __restrict__ gpre,
    const float* __restrict__ whh_f, const float* __restrict__ whh_b,
    const float* __restrict__ bias_f, const float* __restrict__ bias_b,
    float* __restrict__ out)
{
    int dir  = blockIdx.x >> 6;   // grid = 128
    int b    = blockIdx.x & 63;
    int lane = threadIdx.x;
    const float* whh  = dir ? whh_b  : whh_f;
    const float* bias = dir ? bias_b : bias_f;

    int g0 = (lane < 40) ? lane : 39;   // clamp idle lanes to valid memory
    int g1 = g0 + 40;
    float w0[HH], w1[HH];
#pragma unroll
    for (int k = 0; k < HH; k++) {
        w0[k] = whh[g0 * HH + k];
        w1[k] = whh[g1 * HH + k];
    }
    float b0 = bias[g0], b1 = bias[g1];

    const float* gp = gpre + (size_t)b * WW * NOUT + dir * G4;
    float h = 0.f, c = 0.f;             // live in lanes < 20
    int w = dir ? (WW - 1) : 0;
    int stepd = dir ? -1 : 1;
    float pre0 = gp[(size_t)w * NOUT + g0];
    float pre1 = gp[(size_t)w * NOUT + g1];

    for (int s = 0; s < WW; ++s) {
        int wn = w + stepd;
        float n0 = 0.f, n1 = 0.f;
        if (s + 1 < WW) {               // prefetch next step (independent of h)
            n0 = gp[(size_t)wn * NOUT + g0];
            n1 = gp[(size_t)wn * NOUT + g1];
        }
        float a0 = pre0 + b0, a1 = pre1 + b1;
#pragma unroll
        for (int k = 0; k < HH; k++) {
            float hv = __shfl(h, k, 64);
            a0 = fmaf(hv, w0[k], a0);
            a1 = fmaf(hv, w1[k], a1);
        }
        int src = (lane % 20) + 20;
        float fv = __shfl(a0, src, 64);
        float ov = __shfl(a1, src, 64);
        if (lane < HH) {
            c = fsig(fv) * c + fsig(a0) * ftanh(a1);
            h = fsig(ov) * ftanh(c);
            out[((size_t)b * WW + w) * (2 * HH) + dir * HH + lane] = h;
        }
        pre0 = n0; pre1 = n1;
        w = wn;
    }
}

extern "C" void kernel_launch(void* const* d_in, const int* in_sizes, int n_in,
                              void* d_out, int out_size, void* d_ws, size_t ws_size,
                              hipStream_t stream) {
    const float* hiddens   = (const float*)d_in[0];
    const int*   bert2toks = (const int*)d_in[1];
    const int*   cap_inds  = (const int*)d_in[2];
    const float* cap_table = (const float*)d_in[3];
    const float* w_ih_f    = (const float*)d_in[4];
    const float* w_hh_f    = (const float*)d_in[5];
    const float* b_f       = (const float*)d_in[6];
    const float* w_ih_b    = (const float*)d_in[7];
    const float* w_hh_b    = (const float*)d_in[8];
    const float* b_b       = (const float*)d_in[9];
    float* out = (float*)d_out;

    _Float16* x    = (_Float16*)d_ws;
    _Float16* wpad = (_Float16*)((char*)d_ws + X_BYTES);
    float*    gpre = (float*)((char*)d_ws + X_BYTES + WP_BYTES);

    k_pad_w<<<NOUT, 256, 0, stream>>>(w_ih_f, w_ih_b, wpad);
    k_build_x<<<BB * WW, 256, 0, stream>>>(hiddens, bert2toks, cap_inds, cap_table, x);
    k_gemm<<<(BB * WW) / BMT, 256, 0, stream>>>(x, wpad, gpre);
    k_lstm<<<128, 64, 0, stream>>>(gpre, w_hh_f, w_hh_b, b_f, b_b, out);
}